// Round 3
// baseline (155.138 us; speedup 1.0000x reference)
//
#include <hip/hip_runtime.h>

// ShiftVarConv2D: out[n,m,y,x] = sum_{di,dj} coded[n,y+di-1,x+dj-1] *
//                 W[(y%8)*8+(x%8), m, di*3+dj] + bias[g*16+m]
// N=128, H=128, SUB=16 out channels, 3x3 window, weights vary with (y%8,x%8).
//
// This version: blocks own 8 CONSECUTIVE rows (ybase=8*k0), so thread-row
// r == b1 and every wave store is 1024 B contiguous (block: 4 KB chunks),
// vs 512 B @ 4 KB stride in the b1-blocked layout. Weights for all 8 b1
// (mh half) are staged as one coalesced 20 KB LDS copy from a pre-transposed
// workspace (wprep_kernel).

#define H 128
#define N_BATCH 128
#define SUB 16

// Wt layout: [mh][b1][mi][80]; within 80: h*40 + i*4 + jj = W[oc, tap i],
// oc = (b1*8 + 4h + jj)*16 + mh*8 + mi; bias at h*40 + 36 + jj.
// Float4-aligned so the main kernel reads each tap as ds_read_b128.
__global__ void wprep_kernel(const float* __restrict__ w,
                             const float* __restrict__ bias,
                             float* __restrict__ Wt) {
    int t = blockIdx.x * blockDim.x + threadIdx.x;   // 0..1023
    if (t >= 1024) return;
    int jj = t & 3;
    int h  = (t >> 2) & 1;
    int mi = (t >> 3) & 7;
    int b1 = (t >> 6) & 7;
    int mh = (t >> 9) & 1;
    int oc = (b1 * 8 + 4 * h + jj) * 16 + mh * 8 + mi;
    float* dst = Wt + ((mh * 8 + b1) * 8 + mi) * 80 + h * 40;
#pragma unroll
    for (int i = 0; i < 9; ++i) dst[i * 4 + jj] = w[oc * 9 + i];
    dst[36 + jj] = bias[oc];
}

// grid = 2048 blocks (n:128, mh:2, k0:8), XCD-swizzled: low 3 bits = n&7.
// block = 256 threads: c = t&31 -> x0 = 4c (32 lanes x float4 = one full row),
// r = t>>5 -> row y = 8*k0 + r (+64 for g=1); b1 = y%8 = r.
// One wave = rows {2w, 2w+1}: each store instr writes 1024 B contiguous.
__global__ __launch_bounds__(256, 4) void shiftconv_kernel(
        const float* __restrict__ x,
        const float* __restrict__ Wt,
        float* __restrict__ out) {
    int bid = blockIdx.x;
    int nlo = bid & 7;            // XCD-swizzle: same n -> same XCD
    int q   = bid >> 3;
    int mh  = q & 1;
    int k0  = (q >> 1) & 7;
    int n   = ((q >> 4) << 3) | nlo;

    // Stage this block's mh-half of the transposed weights: 8 b1 x 8 mi x 80
    // floats = 20 KB, as a straight coalesced vector copy.
    __shared__ float ws[8 * 8 * 80];
    {
        int t = threadIdx.x;
        const float4* src = (const float4*)(Wt + mh * (8 * 8 * 80));
        float4* dst = (float4*)ws;
#pragma unroll
        for (int i = 0; i < 5; ++i) dst[t + 256 * i] = src[t + 256 * i];
    }

    int c  = threadIdx.x & 31;    // x0 = 4c
    int r  = threadIdx.x >> 5;    // 0..7 == row offset == b1
    int x0 = c << 2;
    int h  = c & 1;               // x0 % 8 == 4h -> b2 = 4h + jj
    int y0 = (k0 << 3) + r;       // g=0 row; g=1 row is y0 + 64 (same b1)

    const float* xn = x + (size_t)n * (H * H);

    // in[g][dy][k] = coded[n, yg+dy-1, x0+k-1] (zero padded), k in [0,6)
    // One aligned float4 load per row; halo from neighbor lanes via shuffle.
    float in[2][3][6];
#pragma unroll
    for (int g = 0; g < 2; ++g) {
        int yg = y0 + (g << 6);
#pragma unroll
        for (int dy = 0; dy < 3; ++dy) {
            int ry = yg + dy - 1;
            float4 a = make_float4(0.0f, 0.0f, 0.0f, 0.0f);
            if (ry >= 0 && ry < H) a = *(const float4*)(xn + ry * H + x0);
            in[g][dy][1] = a.x; in[g][dy][2] = a.y;
            in[g][dy][3] = a.z; in[g][dy][4] = a.w;
            float left  = __shfl_up(a.w, 1);    // lane c-1's a.w == row[x0-1]
            float right = __shfl_down(a.x, 1);  // lane c+1's a.x == row[x0+4]
            in[g][dy][0] = (c == 0)  ? 0.0f : left;    // x0-1 < 0 pad
            in[g][dy][5] = (c == 31) ? 0.0f : right;   // x0+4 >= H pad
        }
    }

    __syncthreads();

    float* ob = out + ((size_t)(n * SUB + mh * 8)) * (H * H) + y0 * H + x0;
    const float* wbase = ws + (r * 8) * 80 + h * 40;   // b1 = r

#pragma unroll
    for (int mi = 0; mi < 8; ++mi) {
        const float4* wp = (const float4*)(wbase + mi * 80);
        float4 b4 = wp[9];                    // bias for jj=0..3
        float a0[4] = {b4.x, b4.y, b4.z, b4.w};
        float a1[4] = {b4.x, b4.y, b4.z, b4.w};
#pragma unroll
        for (int dy = 0; dy < 3; ++dy) {
#pragma unroll
            for (int dj = 0; dj < 3; ++dj) {
                float4 w4 = wp[dy * 3 + dj];  // one ds_read_b128 = 4 weights
                a0[0] = fmaf(in[0][dy][dj + 0], w4.x, a0[0]);
                a0[1] = fmaf(in[0][dy][dj + 1], w4.y, a0[1]);
                a0[2] = fmaf(in[0][dy][dj + 2], w4.z, a0[2]);
                a0[3] = fmaf(in[0][dy][dj + 3], w4.w, a0[3]);
                a1[0] = fmaf(in[1][dy][dj + 0], w4.x, a1[0]);
                a1[1] = fmaf(in[1][dy][dj + 1], w4.y, a1[1]);
                a1[2] = fmaf(in[1][dy][dj + 2], w4.z, a1[2]);
                a1[3] = fmaf(in[1][dy][dj + 3], w4.w, a1[3]);
            }
        }
        float* p = ob + (size_t)mi * (H * H);
        *(float4*)(p)          = make_float4(a0[0], a0[1], a0[2], a0[3]);
        *(float4*)(p + 64 * H) = make_float4(a1[0], a1[1], a1[2], a1[3]);
    }
}

extern "C" void kernel_launch(void* const* d_in, const int* in_sizes, int n_in,
                              void* d_out, int out_size, void* d_ws, size_t ws_size,
                              hipStream_t stream) {
    const float* coded  = (const float*)d_in[0];
    const float* weight = (const float*)d_in[1];
    const float* bias   = (const float*)d_in[2];
    float* out = (float*)d_out;
    float* Wt  = (float*)d_ws;   // 2*8*8*80*4 = 40960 bytes

    wprep_kernel<<<4, 256, 0, stream>>>(weight, bias, Wt);
    shiftconv_kernel<<<N_BATCH * 2 * 8, 256, 0, stream>>>(coded, Wt, out);
}

// Round 4
// 141.553 us; speedup vs baseline: 1.0960x; 1.0960x over previous
//
#include <hip/hip_runtime.h>

// ShiftVarConv2D: out[n,m,y,x] = sum_{di,dj} coded[n,y+di-1,x+dj-1] *
//                 W[(y%8)*8+(x%8), m, di*3+dj] + bias[g*16+m]
// N=128, H=128, SUB=16 out channels, 3x3 window, weights vary with (y%8,x%8).
//
// R4: single kernel, single generation. Grid = 1024 blocks (n:128, b1:8) =
// exactly 4 blocks/CU on 256 CUs -> one launch ramp, one cold-load phase.
// Each block computes ALL 16 m-planes for its 16 rows (y = b1+8r, +64),
// halving input traffic and amortizing staging/sync over 2x the output.

#define H 128
#define N_BATCH 128
#define SUB 16

// block = 256 threads: c = t&31 -> x0 = 4c (one float4 of output),
// r = t>>5 -> rows y0 = b1+8r and y0+64 (same y%8 -> same weights).
// Weight staging (inline, 5 KB): ws[m*80 + h*40 + i*4 + jj] = W[oc, tap i],
// oc = (b1*8 + 4h + jj)*16 + m; bias at h*40+36+jj. Float4-aligned so the
// inner loop reads each tap as one ds_read_b128 (broadcast, conflict-free).
__global__ __launch_bounds__(256, 4) void shiftconv_kernel(
        const float* __restrict__ x,
        const float* __restrict__ w,
        const float* __restrict__ bias,
        float* __restrict__ out) {
    int bid = blockIdx.x;
    int nlo = bid & 7;            // XCD-swizzle: same n -> same XCD
    int q   = bid >> 3;
    int b1  = q & 7;
    int n   = ((q >> 3) << 3) | nlo;

    // Stage + transpose this block's weights: 16 m x 80 floats = 5120 B.
    __shared__ float ws[16 * 80];
    {
        int t = threadIdx.x;
        if (t < 128) {
            int m  = t >> 3;          // 0..15
            int h  = (t >> 2) & 1;    // 0..1
            int jj = t & 3;           // 0..3
            int oc = (b1 * 8 + 4 * h + jj) * 16 + m;
            float* dst = ws + m * 80 + h * 40;
            const float* src = w + oc * 9;
#pragma unroll
            for (int i = 0; i < 9; ++i) dst[i * 4 + jj] = src[i];
            dst[36 + jj] = bias[oc];
        }
    }

    int c  = threadIdx.x & 31;    // x0 = 4c
    int r  = threadIdx.x >> 5;    // 0..7
    int x0 = c << 2;
    int h  = c & 1;               // x0 % 8 == 4h -> b2 = 4h + jj
    int y0 = b1 + (r << 3);       // g=0 row; g=1 row is y0 + 64 (same b1)

    const float* xn = x + (size_t)n * (H * H);

    // in[g][dy][k] = coded[n, yg+dy-1, x0+k-1] (zero padded), k in [0,6)
    // One aligned float4 load per row; halo from neighbor lanes via shuffle.
    float in[2][3][6];
#pragma unroll
    for (int g = 0; g < 2; ++g) {
        int yg = y0 + (g << 6);
#pragma unroll
        for (int dy = 0; dy < 3; ++dy) {
            int ry = yg + dy - 1;
            float4 a = make_float4(0.0f, 0.0f, 0.0f, 0.0f);
            if (ry >= 0 && ry < H) a = *(const float4*)(xn + ry * H + x0);
            in[g][dy][1] = a.x; in[g][dy][2] = a.y;
            in[g][dy][3] = a.z; in[g][dy][4] = a.w;
            float left  = __shfl_up(a.w, 1);    // lane c-1's a.w == row[x0-1]
            float right = __shfl_down(a.x, 1);  // lane c+1's a.x == row[x0+4]
            in[g][dy][0] = (c == 0)  ? 0.0f : left;    // x0-1 < 0 pad
            in[g][dy][5] = (c == 31) ? 0.0f : right;   // x0+4 >= H pad
        }
    }

    __syncthreads();

    float* ob = out + ((size_t)n * SUB) * (H * H) + y0 * H + x0;

#pragma unroll
    for (int mi = 0; mi < 16; ++mi) {
        const float4* wp = (const float4*)(ws + mi * 80 + h * 40);
        float4 b4 = wp[9];                    // bias for jj=0..3
        float a0[4] = {b4.x, b4.y, b4.z, b4.w};
        float a1[4] = {b4.x, b4.y, b4.z, b4.w};
#pragma unroll
        for (int dy = 0; dy < 3; ++dy) {
#pragma unroll
            for (int dj = 0; dj < 3; ++dj) {
                float4 w4 = wp[dy * 3 + dj];  // one ds_read_b128 = 4 weights
                a0[0] = fmaf(in[0][dy][dj + 0], w4.x, a0[0]);
                a0[1] = fmaf(in[0][dy][dj + 1], w4.y, a0[1]);
                a0[2] = fmaf(in[0][dy][dj + 2], w4.z, a0[2]);
                a0[3] = fmaf(in[0][dy][dj + 3], w4.w, a0[3]);
                a1[0] = fmaf(in[1][dy][dj + 0], w4.x, a1[0]);
                a1[1] = fmaf(in[1][dy][dj + 1], w4.y, a1[1]);
                a1[2] = fmaf(in[1][dy][dj + 2], w4.z, a1[2]);
                a1[3] = fmaf(in[1][dy][dj + 3], w4.w, a1[3]);
            }
        }
        float* p = ob + (size_t)mi * (H * H);
        *(float4*)(p)          = make_float4(a0[0], a0[1], a0[2], a0[3]);
        *(float4*)(p + 64 * H) = make_float4(a1[0], a1[1], a1[2], a1[3]);
    }
}

extern "C" void kernel_launch(void* const* d_in, const int* in_sizes, int n_in,
                              void* d_out, int out_size, void* d_ws, size_t ws_size,
                              hipStream_t stream) {
    const float* coded  = (const float*)d_in[0];
    const float* weight = (const float*)d_in[1];
    const float* bias   = (const float*)d_in[2];
    float* out = (float*)d_out;

    shiftconv_kernel<<<N_BATCH * 8, 256, 0, stream>>>(coded, weight, bias, out);
}